// Round 1
// baseline (152.027 us; speedup 1.0000x reference)
//
#include <hip/hip_runtime.h>
#include <math.h>

// Pairwise distances over edges:
//   d[e] = || R[idx_i[e]] - R[idx_j[e]] ||_2
//
// Bottleneck analysis (round 0 counters): 842 GB/s (10.5% HBM), VALUBusy 6%,
// VGPR=20 -> compiler serialized the 8 gathers per thread; kernel is
// gather-latency bound, ~3x off the ~21us TCP request-rate floor.
//
// This version:
//  1. Pads R [N,3] -> R4 [N,4] (16B aligned) in workspace: each endpoint
//     gather is ONE aligned global_load_dwordx4 (no line splits, no x2+x1).
//  2. Issues all 8 endpoint gathers back-to-back into live registers
//     (4x memory-level parallelism per thread) before any arithmetic.
//  3. Nontemporal index loads / output stores so 77MB of streaming traffic
//     doesn't evict the 1.6MB R4 table from L2.

typedef int   iv4 __attribute__((ext_vector_type(4)));
typedef float fv4 __attribute__((ext_vector_type(4)));

__global__ __launch_bounds__(256) void pad_R_kernel(
    const float* __restrict__ R, fv4* __restrict__ R4, int n_atoms)
{
    const int i = blockIdx.x * blockDim.x + threadIdx.x;
    if (i < n_atoms) {
        fv4 v;
        v.x = R[3 * i + 0];
        v.y = R[3 * i + 1];
        v.z = R[3 * i + 2];
        v.w = 0.0f;
        R4[i] = v;
    }
}

__device__ __forceinline__ float edge_dist(fv4 A, fv4 B)
{
    const float dx = A.x - B.x, dy = A.y - B.y, dz = A.z - B.z;
    return sqrtf(dx * dx + dy * dy + dz * dz);
}

__global__ __launch_bounds__(256) void pairwise_dist4_kernel(
    const fv4* __restrict__ R4,
    const int* __restrict__ idx_i,
    const int* __restrict__ idx_j,
    float* __restrict__ out,
    int n_edges)
{
    const int quad = blockIdx.x * blockDim.x + threadIdx.x;
    const int n_quads = n_edges >> 2;

    if (quad < n_quads) {
        const iv4 a = __builtin_nontemporal_load((const iv4*)idx_i + quad);
        const iv4 b = __builtin_nontemporal_load((const iv4*)idx_j + quad);

        // All 8 gathers independent and issued before any use -> one
        // s_waitcnt covers 8 in-flight dwordx4 loads (vs 20-VGPR serial
        // load->wait->compute in the previous version).
        const fv4 A0 = R4[a.x];
        const fv4 B0 = R4[b.x];
        const fv4 A1 = R4[a.y];
        const fv4 B1 = R4[b.y];
        const fv4 A2 = R4[a.z];
        const fv4 B2 = R4[b.z];
        const fv4 A3 = R4[a.w];
        const fv4 B3 = R4[b.w];

        fv4 o;
        o.x = edge_dist(A0, B0);
        o.y = edge_dist(A1, B1);
        o.z = edge_dist(A2, B2);
        o.w = edge_dist(A3, B3);
        __builtin_nontemporal_store(o, (fv4*)out + quad);
    }

    // Tail: edges not covered by the quad loop (n_edges % 4).
    const int tail_start = n_quads << 2;
    const int tail = n_edges - tail_start;
    if (tail > 0 && quad < tail) {
        const int e = tail_start + quad;
        const fv4 A = R4[idx_i[e]];
        const fv4 B = R4[idx_j[e]];
        out[e] = edge_dist(A, B);
    }
}

// Fallback (workspace too small for the padded table): previous kernel.
__global__ __launch_bounds__(256) void pairwise_dist_kernel(
    const float* __restrict__ R,
    const int* __restrict__ idx_i,
    const int* __restrict__ idx_j,
    float* __restrict__ out,
    int n_edges)
{
    const int quad = blockIdx.x * blockDim.x + threadIdx.x;
    const int n_quads = n_edges >> 2;

    if (quad < n_quads) {
        const int4 a = ((const int4*)idx_i)[quad];
        const int4 b = ((const int4*)idx_j)[quad];
        float4 o;
        {
            const float* pa = R + 3 * (long)a.x;
            const float* pb = R + 3 * (long)b.x;
            float dx = pa[0] - pb[0], dy = pa[1] - pb[1], dz = pa[2] - pb[2];
            o.x = sqrtf(dx * dx + dy * dy + dz * dz);
        }
        {
            const float* pa = R + 3 * (long)a.y;
            const float* pb = R + 3 * (long)b.y;
            float dx = pa[0] - pb[0], dy = pa[1] - pb[1], dz = pa[2] - pb[2];
            o.y = sqrtf(dx * dx + dy * dy + dz * dz);
        }
        {
            const float* pa = R + 3 * (long)a.z;
            const float* pb = R + 3 * (long)b.z;
            float dx = pa[0] - pb[0], dy = pa[1] - pb[1], dz = pa[2] - pb[2];
            o.z = sqrtf(dx * dx + dy * dy + dz * dz);
        }
        {
            const float* pa = R + 3 * (long)a.w;
            const float* pb = R + 3 * (long)b.w;
            float dx = pa[0] - pb[0], dy = pa[1] - pb[1], dz = pa[2] - pb[2];
            o.w = sqrtf(dx * dx + dy * dy + dz * dz);
        }
        ((float4*)out)[quad] = o;
    }

    const int tail_start = n_quads << 2;
    const int tail = n_edges - tail_start;
    if (tail > 0 && quad < tail) {
        const int e = tail_start + quad;
        const int ia = idx_i[e], ib = idx_j[e];
        const float* pa = R + 3 * (long)ia;
        const float* pb = R + 3 * (long)ib;
        float dx = pa[0] - pb[0], dy = pa[1] - pb[1], dz = pa[2] - pb[2];
        out[e] = sqrtf(dx * dx + dy * dy + dz * dz);
    }
}

extern "C" void kernel_launch(void* const* d_in, const int* in_sizes, int n_in,
                              void* d_out, int out_size, void* d_ws, size_t ws_size,
                              hipStream_t stream)
{
    const float* R     = (const float*)d_in[0];
    const int*   idx_i = (const int*)d_in[1];
    const int*   idx_j = (const int*)d_in[2];
    float*       out   = (float*)d_out;

    const int n_edges = in_sizes[1];            // 6,400,000

    // in_sizes[0] may be rows (100000) or flattened elements (300000).
    // 100000 % 3 == 1, 300000 % 3 == 0 -> disambiguate by divisibility.
    const int n0 = in_sizes[0];
    const int n_atoms = (n0 % 3 == 0) ? n0 / 3 : n0;

    const int n_quads = (n_edges + 3) >> 2;
    const int block   = 256;
    int grid = (n_quads + block - 1) / block;
    if (grid < 1) grid = 1;

    const size_t pad_bytes = (size_t)n_atoms * sizeof(fv4);
    if (d_ws != nullptr && ws_size >= pad_bytes) {
        fv4* R4 = (fv4*)d_ws;
        const int pad_grid = (n_atoms + block - 1) / block;
        pad_R_kernel<<<pad_grid, block, 0, stream>>>(R, R4, n_atoms);
        pairwise_dist4_kernel<<<grid, block, 0, stream>>>(R4, idx_i, idx_j, out, n_edges);
    } else {
        pairwise_dist_kernel<<<grid, block, 0, stream>>>(R, idx_i, idx_j, out, n_edges);
    }
}

// Round 2
// 146.103 us; speedup vs baseline: 1.0405x; 1.0405x over previous
//
#include <hip/hip_runtime.h>
#include <math.h>

// Pairwise distances over edges:
//   d[e] = || R[idx_i[e]] - R[idx_j[e]] ||_2
//
// Round-1 post-mortem: padded R4 table changed nothing (69us, VGPR still 20).
// VGPR=20 proves the compiler re-serialized the 8 gathers (8 x dwordx4 needs
// >=32 VGPRs of payload) into load-pair -> wait -> compute, eating ~300cy of
// L2 latency 4x per thread. Working set is L3-resident (FETCH 31MB < 51MB of
// idx), so HBM is irrelevant; the binding resource is the divergent-gather
// path (12.8M random 16B lane-gathers, floor ~21-24us).
//
// Round-2 change: an empty asm fence consuming all eight fv4 gather results
// ("+v" constraints) between the loads and the math. Compiler must have all
// 8 loads issued before the fence -> 8 back-to-back issues, ONE s_waitcnt,
// one latency exposure per thread instead of four. VGPR ~50, still 8
// waves/SIMD.

typedef int   iv4 __attribute__((ext_vector_type(4)));
typedef float fv4 __attribute__((ext_vector_type(4)));

__global__ __launch_bounds__(256) void pad_R_kernel(
    const float* __restrict__ R, fv4* __restrict__ R4, int n_atoms)
{
    const int i = blockIdx.x * blockDim.x + threadIdx.x;
    if (i < n_atoms) {
        fv4 v;
        v.x = R[3 * i + 0];
        v.y = R[3 * i + 1];
        v.z = R[3 * i + 2];
        v.w = 0.0f;
        R4[i] = v;
    }
}

__device__ __forceinline__ float edge_dist(fv4 A, fv4 B)
{
    const float dx = A.x - B.x, dy = A.y - B.y, dz = A.z - B.z;
    return sqrtf(dx * dx + dy * dy + dz * dz);
}

__global__ __launch_bounds__(256) void pairwise_dist4_kernel(
    const fv4* __restrict__ R4,
    const int* __restrict__ idx_i,
    const int* __restrict__ idx_j,
    float* __restrict__ out,
    int n_edges)
{
    const int quad = blockIdx.x * blockDim.x + threadIdx.x;
    const int n_quads = n_edges >> 2;

    if (quad < n_quads) {
        const iv4 a = __builtin_nontemporal_load((const iv4*)idx_i + quad);
        const iv4 b = __builtin_nontemporal_load((const iv4*)idx_j + quad);

        fv4 A0 = R4[a.x];
        fv4 B0 = R4[b.x];
        fv4 A1 = R4[a.y];
        fv4 B1 = R4[b.y];
        fv4 A2 = R4[a.z];
        fv4 B2 = R4[b.z];
        fv4 A3 = R4[a.w];
        fv4 B3 = R4[b.w];

        // MLP fence: forces all 8 gather results to be materialized HERE.
        // Loads cannot be sunk past this point and interleaved with the
        // arithmetic -> 8 issues, one s_waitcnt vmcnt(0), one latency hit.
        asm volatile("" : "+v"(A0), "+v"(B0), "+v"(A1), "+v"(B1),
                          "+v"(A2), "+v"(B2), "+v"(A3), "+v"(B3));

        fv4 o;
        o.x = edge_dist(A0, B0);
        o.y = edge_dist(A1, B1);
        o.z = edge_dist(A2, B2);
        o.w = edge_dist(A3, B3);
        __builtin_nontemporal_store(o, (fv4*)out + quad);
    }

    // Tail: edges not covered by the quad loop (n_edges % 4).
    const int tail_start = n_quads << 2;
    const int tail = n_edges - tail_start;
    if (tail > 0 && quad < tail) {
        const int e = tail_start + quad;
        const fv4 A = R4[idx_i[e]];
        const fv4 B = R4[idx_j[e]];
        out[e] = edge_dist(A, B);
    }
}

// Fallback (workspace too small for the padded table).
__global__ __launch_bounds__(256) void pairwise_dist_kernel(
    const float* __restrict__ R,
    const int* __restrict__ idx_i,
    const int* __restrict__ idx_j,
    float* __restrict__ out,
    int n_edges)
{
    const int quad = blockIdx.x * blockDim.x + threadIdx.x;
    const int n_quads = n_edges >> 2;

    if (quad < n_quads) {
        const int4 a = ((const int4*)idx_i)[quad];
        const int4 b = ((const int4*)idx_j)[quad];
        float4 o;
        {
            const float* pa = R + 3 * (long)a.x;
            const float* pb = R + 3 * (long)b.x;
            float dx = pa[0] - pb[0], dy = pa[1] - pb[1], dz = pa[2] - pb[2];
            o.x = sqrtf(dx * dx + dy * dy + dz * dz);
        }
        {
            const float* pa = R + 3 * (long)a.y;
            const float* pb = R + 3 * (long)b.y;
            float dx = pa[0] - pb[0], dy = pa[1] - pb[1], dz = pa[2] - pb[2];
            o.y = sqrtf(dx * dx + dy * dy + dz * dz);
        }
        {
            const float* pa = R + 3 * (long)a.z;
            const float* pb = R + 3 * (long)b.z;
            float dx = pa[0] - pb[0], dy = pa[1] - pb[1], dz = pa[2] - pb[2];
            o.z = sqrtf(dx * dx + dy * dy + dz * dz);
        }
        {
            const float* pa = R + 3 * (long)a.w;
            const float* pb = R + 3 * (long)b.w;
            float dx = pa[0] - pb[0], dy = pa[1] - pb[1], dz = pa[2] - pb[2];
            o.w = sqrtf(dx * dx + dy * dy + dz * dz);
        }
        ((float4*)out)[quad] = o;
    }

    const int tail_start = n_quads << 2;
    const int tail = n_edges - tail_start;
    if (tail > 0 && quad < tail) {
        const int e = tail_start + quad;
        const int ia = idx_i[e], ib = idx_j[e];
        const float* pa = R + 3 * (long)ia;
        const float* pb = R + 3 * (long)ib;
        float dx = pa[0] - pb[0], dy = pa[1] - pb[1], dz = pa[2] - pb[2];
        out[e] = sqrtf(dx * dx + dy * dy + dz * dz);
    }
}

extern "C" void kernel_launch(void* const* d_in, const int* in_sizes, int n_in,
                              void* d_out, int out_size, void* d_ws, size_t ws_size,
                              hipStream_t stream)
{
    const float* R     = (const float*)d_in[0];
    const int*   idx_i = (const int*)d_in[1];
    const int*   idx_j = (const int*)d_in[2];
    float*       out   = (float*)d_out;

    const int n_edges = in_sizes[1];            // 6,400,000

    // in_sizes[0] may be rows (100000) or flattened elements (300000).
    const int n0 = in_sizes[0];
    const int n_atoms = (n0 % 3 == 0) ? n0 / 3 : n0;

    const int n_quads = (n_edges + 3) >> 2;
    const int block   = 256;
    int grid = (n_quads + block - 1) / block;
    if (grid < 1) grid = 1;

    const size_t pad_bytes = (size_t)n_atoms * sizeof(fv4);
    if (d_ws != nullptr && ws_size >= pad_bytes) {
        fv4* R4 = (fv4*)d_ws;
        const int pad_grid = (n_atoms + block - 1) / block;
        pad_R_kernel<<<pad_grid, block, 0, stream>>>(R, R4, n_atoms);
        pairwise_dist4_kernel<<<grid, block, 0, stream>>>(R4, idx_i, idx_j, out, n_edges);
    } else {
        pairwise_dist_kernel<<<grid, block, 0, stream>>>(R, idx_i, idx_j, out, n_edges);
    }
}